// Round 2
// baseline (280.281 us; speedup 1.0000x reference)
//
#include <hip/hip_runtime.h>

// Reaction-diffusion (vegetation NCA) single Euler step, fused.
// w' = w + (lap(w) - 0.2 w + 1.845 - U) * 1e-4,  U = w*b*(1+3b)
// b' = b + (0.05 lap(b) - 0.3 T b + 0.449 U) * 1e-4
// Laplacian: 5-point, replicate (edge) padding.

namespace {
constexpr int IMGS = 16;
constexpr int H = 1024;
constexpr int W = 1024;
constexpr size_t PLANE = (size_t)H * W;
}

__global__ __launch_bounds__(256) void nca_step(
    const float* __restrict__ wg, const float* __restrict__ bg,
    const float* __restrict__ Tg, float* __restrict__ owg,
    float* __restrict__ obg)
{
    // XCD-aware swizzle: grid = 16384 = 8 XCDs * 2048, divisible -> simple
    // bijective remap. Each XCD gets a contiguous band (2 whole images), so
    // up/down halo rows are L2-local.
    const int nwg = gridDim.x;
    const int cpx = nwg >> 3;                       // blocks per XCD
    const int bid = blockIdx.x;
    const int swz = (bid & 7) * cpx + (bid >> 3);

    const int img = swz >> 10;                      // / H
    const int y   = swz & (H - 1);
    const int t   = threadIdx.x;
    const int x0  = t << 2;                         // 4 floats per thread

    const float* wp = wg + (size_t)img * PLANE;
    const float* bp = bg + (size_t)img * PLANE;
    const float* Tp = Tg + (size_t)img * PLANE;

    const int yu = (y > 0)     ? (y - 1) : 0;       // replicate padding
    const int yd = (y < H - 1) ? (y + 1) : (H - 1);

    const float* wrow = wp + (size_t)y * W;
    const float* brow = bp + (size_t)y * W;

    const float4 cw = *(const float4*)(wrow + x0);
    const float4 uw = *(const float4*)(wp + (size_t)yu * W + x0);
    const float4 dw = *(const float4*)(wp + (size_t)yd * W + x0);
    const float4 cb = *(const float4*)(brow + x0);
    const float4 ub = *(const float4*)(bp + (size_t)yu * W + x0);
    const float4 db = *(const float4*)(bp + (size_t)yd * W + x0);
    const float4 cT = *(const float4*)(Tp + (size_t)y * W + x0);

    // Left/right horizontal neighbors: two scalar loads per field (cache
    // hits -- same lines as the vector loads above). Replicate at row edges.
    const float wl = (x0 > 0)     ? wrow[x0 - 1] : cw.x;
    const float wr = (x0 + 4 < W) ? wrow[x0 + 4] : cw.w;
    const float bl = (x0 > 0)     ? brow[x0 - 1] : cb.x;
    const float br = (x0 + 4 < W) ? brow[x0 + 4] : cb.w;

    // 5-point Laplacians (replicate padding handled via yu/yd/wl/wr).
    float lw[4], lb[4];
    lw[0] = uw.x + dw.x + wl   + cw.y - 4.0f * cw.x;
    lw[1] = uw.y + dw.y + cw.x + cw.z - 4.0f * cw.y;
    lw[2] = uw.z + dw.z + cw.y + cw.w - 4.0f * cw.z;
    lw[3] = uw.w + dw.w + cw.z + wr   - 4.0f * cw.w;

    lb[0] = ub.x + db.x + bl   + cb.y - 4.0f * cb.x;
    lb[1] = ub.y + db.y + cb.x + cb.z - 4.0f * cb.y;
    lb[2] = ub.z + db.z + cb.y + cb.w - 4.0f * cb.z;
    lb[3] = ub.w + db.w + cb.z + br   - 4.0f * cb.w;

    const float wv[4] = {cw.x, cw.y, cw.z, cw.w};
    const float bv[4] = {cb.x, cb.y, cb.z, cb.w};
    const float Tv[4] = {cT.x, cT.y, cT.z, cT.w};

    float4 ow4, ob4;
    float* owp = &ow4.x;
    float* obp = &ob4.x;
#pragma unroll
    for (int i = 0; i < 4; ++i) {
        const float up = wv[i] * bv[i] * (1.0f + 3.0f * bv[i]);
        owp[i] = wv[i] + (lw[i] - 0.2f * wv[i] + 1.845f - up) * 1e-4f;
        obp[i] = bv[i] + (0.05f * lb[i] - 0.3f * Tv[i] * bv[i] + 0.449f * up) * 1e-4f;
    }

    const size_t oidx = (size_t)img * PLANE + (size_t)y * W + x0;
    *(float4*)(owg + oidx) = ow4;
    *(float4*)(obg + oidx) = ob4;
}

extern "C" void kernel_launch(void* const* d_in, const int* in_sizes, int n_in,
                              void* d_out, int out_size, void* d_ws, size_t ws_size,
                              hipStream_t stream) {
    const float* w = (const float*)d_in[0];
    const float* b = (const float*)d_in[1];
    const float* T = (const float*)d_in[2];
    float* ow = (float*)d_out;                      // w_new first (return order)
    float* ob = ow + (size_t)IMGS * PLANE;          // then b_new

    dim3 grid(IMGS * H);                            // one block per (img,row)
    dim3 block(W / 4);                              // 256 threads x float4
    nca_step<<<grid, block, 0, stream>>>(w, b, T, ow, ob);
}